// Round 2
// baseline (321.854 us; speedup 1.0000x reference)
//
#include <hip/hip_runtime.h>
#include <stdint.h>

#define NPROP 2048
#define NCLS  2
#define KDET  100
#define BT    256

// decode the monotone-encoded score from the high word of a sort key
__device__ __forceinline__ float dec_score(uint64_t k) {
    uint32_t u = ~(uint32_t)(k >> 32);
    uint32_t bits = (u & 0x80000000u) ? (u & 0x7FFFFFFFu) : ~u;
    return __uint_as_float(bits);
}

__global__ __launch_bounds__(BT) void PRISM_71511205479155_kernel(
    const float* __restrict__ clss,   // [B,N,2]
    const float* __restrict__ regs,   // [B,N,4]
    const float* __restrict__ qlts,   // [B,N]
    const float* __restrict__ props,  // [B,N,4]
    float* __restrict__ out,          // boxes[B*K*4] | scores[B*K] | classes[B*K]
    int B)
{
    __shared__ float4   sbox[NPROP];        // decoded+clipped boxes (orig coords)
    __shared__ uint64_t skey[NPROP];        // (~enc(masked))<<32 | idx  (ascending = score desc, idx asc)
    __shared__ unsigned char ssupp[NPROP];  // suppression flags (sorted order)
    __shared__ int s_maxc;
    __shared__ int s_cur, s_kept, s_keeper, s_done, s_nvalid;

    const int b   = blockIdx.x;
    const int tid = threadIdx.x;
    const float CLIPV = 4.135166556742356f;   // log(1000/16)

    if (tid == 0) { s_maxc = 0; s_cur = 0; s_kept = 0; s_nvalid = NPROP; }
    __syncthreads();

    // ---- Phase A: decode, clip, score, build sort keys ----
    for (int i = tid; i < NPROP; i += BT) {
        float4 p = ((const float4*)props)[b * NPROP + i];
        float4 r = ((const float4*)regs)[b * NPROP + i];
        float c0 = clss[((size_t)b * NPROP + i) * 2 + 0];
        float c1 = clss[((size_t)b * NPROP + i) * 2 + 1];
        float qv = qlts[(size_t)b * NPROP + i];

        float w  = __fsub_rn(p.z, p.x);
        float h  = __fsub_rn(p.w, p.y);
        float cx = __fadd_rn(p.x, __fmul_rn(0.5f, w));
        float cy = __fadd_rn(p.y, __fmul_rn(0.5f, h));
        float dx = __fdiv_rn(r.x, 10.0f);
        float dy = __fdiv_rn(r.y, 10.0f);
        float dw = fminf(__fdiv_rn(r.z, 5.0f), CLIPV);
        float dh = fminf(__fdiv_rn(r.w, 5.0f), CLIPV);
        float pcx = __fadd_rn(__fmul_rn(dx, w), cx);
        float pcy = __fadd_rn(__fmul_rn(dy, h), cy);
        float pw  = __fmul_rn(expf(dw), w);
        float ph  = __fmul_rn(expf(dh), h);
        float x1 = __fsub_rn(pcx, __fmul_rn(0.5f, pw));
        float y1 = __fsub_rn(pcy, __fmul_rn(0.5f, ph));
        float x2 = __fadd_rn(pcx, __fmul_rn(0.5f, pw));
        float y2 = __fadd_rn(pcy, __fmul_rn(0.5f, ph));
        x1 = fminf(fmaxf(x1, 0.0f), 512.0f);
        y1 = fminf(fmaxf(y1, 0.0f), 512.0f);
        x2 = fminf(fmaxf(x2, 0.0f), 512.0f);
        y2 = fminf(fmaxf(y2, 0.0f), 512.0f);
        bool small_ok = (__fsub_rn(x2, x1) >= 0.01f) && (__fsub_rn(y2, y1) >= 0.01f);

        // raw = softmax(c)[1]  (max-subtracted, like jax.nn.softmax)
        float m  = fmaxf(c0, c1);
        float e0 = expf(__fsub_rn(c0, m));
        float e1 = expf(__fsub_rn(c1, m));
        float raw = __fdiv_rn(e1, __fadd_rn(e0, e1));
        float sq  = __fdiv_rn(1.0f, __fadd_rn(1.0f, expf(-qv)));
        float score = __fmul_rn(sq, raw);
        bool valid = (raw > 0.05f) && small_ok;
        float masked = valid ? score : -1.0f;

        sbox[i] = make_float4(x1, y1, x2, y2);
        uint32_t fb = __float_as_uint(masked);
        uint32_t u  = (fb & 0x80000000u) ? ~fb : (fb | 0x80000000u); // monotone encode
        skey[i] = ((uint64_t)(~u) << 32) | (uint32_t)i;              // asc sort = desc score, asc idx
        ssupp[i] = 0;

        // max over all 4 coords (all >= 0 after clip -> int-compare == float-compare)
        int mc = __float_as_int(fmaxf(fmaxf(x1, y1), fmaxf(x2, y2)));
        atomicMax(&s_maxc, mc);
    }
    __syncthreads();
    const float off = __fadd_rn(__int_as_float(s_maxc), 1.0f); // class-1 batched-NMS offset

    // ---- Phase B: bitonic sort of 2048 keys (ascending) ----
    for (int k = 2; k <= NPROP; k <<= 1) {
        for (int j = k >> 1; j > 0; j >>= 1) {
            __syncthreads();
            for (int idx = tid; idx < NPROP; idx += BT) {
                int ixj = idx ^ j;
                if (ixj > idx) {
                    uint64_t a = skey[idx], c = skey[ixj];
                    bool up = ((idx & k) == 0);
                    if ((a > c) == up) { skey[idx] = c; skey[ixj] = a; }
                }
            }
        }
    }
    __syncthreads();

    // ---- valid prefix length: invalid keys have top bit set ----
    for (int idx = tid; idx < NPROP; idx += BT) {
        bool inval      = (skey[idx] >> 63) != 0;
        bool prev_inval = (idx == 0) ? false : ((skey[idx - 1] >> 63) != 0);
        if (inval && !prev_inval) s_nvalid = idx;   // unique writer
    }
    __syncthreads();

    float* out_boxes  = out;
    float* out_scores = out + (size_t)B * KDET * 4;
    float* out_cls    = out + (size_t)B * KDET * 5;

    // ---- Phase C: greedy NMS over valid prefix, emit first K keepers ----
    while (true) {
        __syncthreads();
        if (tid == 0) {
            int p  = s_cur;
            int nv = s_nvalid;
            while (p < nv && ssupp[p]) p++;
            if (p >= nv || s_kept >= KDET) {
                s_done = 1;
            } else {
                s_done = 0;
                s_keeper = p;
                s_cur = p + 1;
                uint64_t kk = skey[p];
                int oi = (int)(uint32_t)kk;
                float4 bx = sbox[oi];
                int slot = s_kept;
                float* ob = out_boxes + ((size_t)b * KDET + slot) * 4;
                ob[0] = bx.x; ob[1] = bx.y; ob[2] = bx.z; ob[3] = bx.w;
                out_scores[(size_t)b * KDET + slot] = dec_score(kk);
                out_cls[(size_t)b * KDET + slot]    = 1.0f;
                s_kept = slot + 1;
            }
        }
        __syncthreads();
        if (s_done) break;

        int p = s_keeper;
        uint64_t kk = skey[p];
        int oi = (int)(uint32_t)kk;
        float4 kb = sbox[oi];
        float kx1 = __fadd_rn(kb.x, off), ky1 = __fadd_rn(kb.y, off);
        float kx2 = __fadd_rn(kb.z, off), ky2 = __fadd_rn(kb.w, off);
        float karea = __fmul_rn(__fsub_rn(kx2, kx1), __fsub_rn(ky2, ky1));

        for (int q = p + 1 + tid; q < s_nvalid; q += BT) {
            if (ssupp[q]) continue;
            int oj = (int)(uint32_t)skey[q];
            float4 qb = sbox[oj];
            float qx1 = __fadd_rn(qb.x, off), qy1 = __fadd_rn(qb.y, off);
            float qx2 = __fadd_rn(qb.z, off), qy2 = __fadd_rn(qb.w, off);
            float qarea = __fmul_rn(__fsub_rn(qx2, qx1), __fsub_rn(qy2, qy1));
            float ltx = fmaxf(kx1, qx1), lty = fmaxf(ky1, qy1);
            float rbx = fminf(kx2, qx2), rby = fminf(ky2, qy2);
            float iw = fmaxf(__fsub_rn(rbx, ltx), 0.0f);
            float ih = fmaxf(__fsub_rn(rby, lty), 0.0f);
            float inter = __fmul_rn(iw, ih);
            float denom = __fadd_rn(__fsub_rn(__fadd_rn(karea, qarea), inter), 1e-9f);
            float iou = __fdiv_rn(inter, denom);
            if (iou > 0.4f) ssupp[q] = 1;
        }
    }
    __syncthreads();

    // ---- zero-fill remaining slots (harness poisons d_out before timing) ----
    int kept = s_kept;
    for (int slot = kept + tid; slot < KDET; slot += BT) {
        float* ob = out_boxes + ((size_t)b * KDET + slot) * 4;
        ob[0] = 0.0f; ob[1] = 0.0f; ob[2] = 0.0f; ob[3] = 0.0f;
        out_scores[(size_t)b * KDET + slot] = 0.0f;
        out_cls[(size_t)b * KDET + slot]    = 0.0f;
    }
}

extern "C" void kernel_launch(void* const* d_in, const int* in_sizes, int n_in,
                              void* d_out, int out_size, void* d_ws, size_t ws_size,
                              hipStream_t stream) {
    const float* clss  = (const float*)d_in[0];  // [B,N,2]
    const float* regs  = (const float*)d_in[1];  // [B,N,4]
    const float* qlts  = (const float*)d_in[2];  // [B,N,1]
    const float* props = (const float*)d_in[3];  // [B,N,4]
    float* out = (float*)d_out;

    int B = in_sizes[0] / (NPROP * NCLS);

    PRISM_71511205479155_kernel<<<B, BT, 0, stream>>>(clss, regs, qlts, props, out, B);
}

// Round 3
// 77.403 us; speedup vs baseline: 4.1582x; 4.1582x over previous
//
#include <hip/hip_runtime.h>
#include <stdint.h>

#define NPROP 2048
#define NCLS  2
#define KDET  100
#define BT    512
#define NMS_TH 0.4f

// decode the monotone-encoded score from the high word of a sort key
__device__ __forceinline__ float dec_score(uint64_t k) {
    uint32_t u = ~(uint32_t)(k >> 32);
    uint32_t bits = (u & 0x80000000u) ? (u & 0x7FFFFFFFu) : ~u;
    return __uint_as_float(bits);
}

// IoU on class-offset boxes, rounding-identical to the reference
__device__ __forceinline__ float iou_off(float4 a, float4 b, float off) {
    float ax1 = __fadd_rn(a.x, off), ay1 = __fadd_rn(a.y, off);
    float ax2 = __fadd_rn(a.z, off), ay2 = __fadd_rn(a.w, off);
    float bx1 = __fadd_rn(b.x, off), by1 = __fadd_rn(b.y, off);
    float bx2 = __fadd_rn(b.z, off), by2 = __fadd_rn(b.w, off);
    float aA = __fmul_rn(__fsub_rn(ax2, ax1), __fsub_rn(ay2, ay1));
    float aB = __fmul_rn(__fsub_rn(bx2, bx1), __fsub_rn(by2, by1));
    float ltx = fmaxf(ax1, bx1), lty = fmaxf(ay1, by1);
    float rbx = fminf(ax2, bx2), rby = fminf(ay2, by2);
    float iw = fmaxf(__fsub_rn(rbx, ltx), 0.0f);
    float ih = fmaxf(__fsub_rn(rby, lty), 0.0f);
    float inter = __fmul_rn(iw, ih);
    float denom = __fadd_rn(__fsub_rn(__fadd_rn(aA, aB), inter), 1e-9f);
    return __fdiv_rn(inter, denom);
}

__global__ __launch_bounds__(BT) void PRISM_71511205479155_kernel(
    const float* __restrict__ clss,   // [B,N,2]
    const float* __restrict__ regs,   // [B,N,4]
    const float* __restrict__ qlts,   // [B,N]
    const float* __restrict__ props,  // [B,N,4]
    float* __restrict__ out,          // boxes[B*K*4] | scores[B*K] | classes[B*K]
    int B)
{
    __shared__ float4   sbox[NPROP];        // decoded+clipped boxes (orig coords)
    __shared__ uint64_t skey[NPROP];        // (~enc(masked))<<32 | idx
    __shared__ unsigned long long s_rowmask[64];
    __shared__ unsigned long long s_insup;
    __shared__ int s_keep[KDET];            // sorted positions of keepers
    __shared__ int s_maxc, s_kept, s_nvalid;

    const int b    = blockIdx.x;
    const int tid  = threadIdx.x;
    const int lane = tid & 63;
    const int wv   = tid >> 6;              // 8 waves
    const float CLIPV = 4.135166556742356f; // log(1000/16)

    if (tid == 0) { s_maxc = 0; s_kept = 0; s_nvalid = NPROP; }
    __syncthreads();

    // ---- Phase A: decode, clip, score, build sort keys ----
    for (int i = tid; i < NPROP; i += BT) {
        float4 p = ((const float4*)props)[b * NPROP + i];
        float4 r = ((const float4*)regs)[b * NPROP + i];
        float c0 = clss[((size_t)b * NPROP + i) * 2 + 0];
        float c1 = clss[((size_t)b * NPROP + i) * 2 + 1];
        float qv = qlts[(size_t)b * NPROP + i];

        float w  = __fsub_rn(p.z, p.x);
        float h  = __fsub_rn(p.w, p.y);
        float cx = __fadd_rn(p.x, __fmul_rn(0.5f, w));
        float cy = __fadd_rn(p.y, __fmul_rn(0.5f, h));
        float dx = __fdiv_rn(r.x, 10.0f);
        float dy = __fdiv_rn(r.y, 10.0f);
        float dw = fminf(__fdiv_rn(r.z, 5.0f), CLIPV);
        float dh = fminf(__fdiv_rn(r.w, 5.0f), CLIPV);
        float pcx = __fadd_rn(__fmul_rn(dx, w), cx);
        float pcy = __fadd_rn(__fmul_rn(dy, h), cy);
        float pw  = __fmul_rn(expf(dw), w);
        float ph  = __fmul_rn(expf(dh), h);
        float x1 = __fsub_rn(pcx, __fmul_rn(0.5f, pw));
        float y1 = __fsub_rn(pcy, __fmul_rn(0.5f, ph));
        float x2 = __fadd_rn(pcx, __fmul_rn(0.5f, pw));
        float y2 = __fadd_rn(pcy, __fmul_rn(0.5f, ph));
        x1 = fminf(fmaxf(x1, 0.0f), 512.0f);
        y1 = fminf(fmaxf(y1, 0.0f), 512.0f);
        x2 = fminf(fmaxf(x2, 0.0f), 512.0f);
        y2 = fminf(fmaxf(y2, 0.0f), 512.0f);
        bool small_ok = (__fsub_rn(x2, x1) >= 0.01f) && (__fsub_rn(y2, y1) >= 0.01f);

        float m  = fmaxf(c0, c1);
        float e0 = expf(__fsub_rn(c0, m));
        float e1 = expf(__fsub_rn(c1, m));
        float raw = __fdiv_rn(e1, __fadd_rn(e0, e1));
        float sq  = __fdiv_rn(1.0f, __fadd_rn(1.0f, expf(-qv)));
        float score = __fmul_rn(sq, raw);
        bool valid = (raw > 0.05f) && small_ok;
        float masked = valid ? score : -1.0f;

        sbox[i] = make_float4(x1, y1, x2, y2);
        uint32_t fb = __float_as_uint(masked);
        uint32_t u  = (fb & 0x80000000u) ? ~fb : (fb | 0x80000000u); // monotone encode
        skey[i] = ((uint64_t)(~u) << 32) | (uint32_t)i;              // asc = score desc, idx asc

        int mc = __float_as_int(fmaxf(fmaxf(x1, y1), fmaxf(x2, y2)));
        atomicMax(&s_maxc, mc);
    }
    __syncthreads();
    const float off = __fadd_rn(__int_as_float(s_maxc), 1.0f); // class-1 batched-NMS offset

    // ---- Phase B: bitonic sort of 2048 keys (ascending) ----
    for (int k = 2; k <= NPROP; k <<= 1) {
        for (int j = k >> 1; j > 0; j >>= 1) {
            __syncthreads();
            for (int idx = tid; idx < NPROP; idx += BT) {
                int ixj = idx ^ j;
                if (ixj > idx) {
                    uint64_t a = skey[idx], cc = skey[ixj];
                    bool up = ((idx & k) == 0);
                    if ((a > cc) == up) { skey[idx] = cc; skey[ixj] = a; }
                }
            }
        }
    }
    __syncthreads();

    // ---- valid prefix length (invalid keys have top bit set) ----
    for (int idx = tid; idx < NPROP; idx += BT) {
        bool inval      = (skey[idx] >> 63) != 0;
        bool prev_inval = (idx == 0) ? false : ((skey[idx - 1] >> 63) != 0);
        if (inval && !prev_inval) s_nvalid = idx;   // unique writer
    }
    __syncthreads();

    // ---- Phase C: windowed greedy NMS (exact reference semantics) ----
    int c = 0;
    while (true) {
        __syncthreads();
        int kept = s_kept;
        int nv   = s_nvalid;
        if (c >= nv || kept >= KDET) break;
        int W = min(64, nv - c);
        if (tid == 0) s_insup = 0ull;
        __syncthreads();

        // this lane's window-candidate box (column l = lane)
        float4 qb = make_float4(0.f, 0.f, 0.f, 0.f);
        bool have = (lane < W);
        if (have) qb = sbox[(uint32_t)skey[c + lane]];

        // in-window pairwise suppression rows via ballot (8 waves x 8 rows)
        for (int i = wv; i < W; i += 8) {
            float4 ib = sbox[(uint32_t)skey[c + i]];
            bool pred = have && (lane > i) && (iou_off(ib, qb, off) > NMS_TH);
            unsigned long long bm = __ballot(pred);
            if (lane == 0) s_rowmask[i] = bm;
        }

        // incoming suppression by prior-window keepers
        if (have) {
            for (int ki = wv; ki < kept; ki += 8) {
                float4 kb = sbox[(uint32_t)skey[s_keep[ki]]];
                if (iou_off(kb, qb, off) > NMS_TH) {
                    atomicOr(&s_insup, 1ull << lane);
                    break;
                }
            }
        }
        __syncthreads();

        // serial greedy resolve of the window — wave 0, all in registers
        if (wv == 0) {
            unsigned long long rm = (lane < W) ? s_rowmask[lane] : 0ull;
            unsigned long long insup = s_insup;
            unsigned long long sup = 0ull;
            int k2 = kept;
            for (int i = 0; i < W; ++i) {
                if (k2 >= KDET) break;
                unsigned long long m = __shfl(rm, i);
                if (!((insup >> i) & 1ull) && !((sup >> i) & 1ull)) {
                    if (lane == 0) s_keep[k2] = c + i;
                    k2++;
                    sup |= m;
                }
            }
            if (lane == 0) s_kept = k2;
        }
        c += W;
    }
    __syncthreads();

    // ---- Phase D: parallel output write + zero-fill ----
    float* out_boxes  = out;
    float* out_scores = out + (size_t)B * KDET * 4;
    float* out_cls    = out + (size_t)B * KDET * 5;
    int kept = s_kept;
    for (int s = tid; s < KDET; s += BT) {
        float* ob = out_boxes + ((size_t)b * KDET + s) * 4;
        if (s < kept) {
            uint64_t kk = skey[s_keep[s]];
            float4 bx = sbox[(uint32_t)kk];
            ob[0] = bx.x; ob[1] = bx.y; ob[2] = bx.z; ob[3] = bx.w;
            out_scores[(size_t)b * KDET + s] = dec_score(kk);
            out_cls[(size_t)b * KDET + s]    = 1.0f;
        } else {
            ob[0] = 0.0f; ob[1] = 0.0f; ob[2] = 0.0f; ob[3] = 0.0f;
            out_scores[(size_t)b * KDET + s] = 0.0f;
            out_cls[(size_t)b * KDET + s]    = 0.0f;
        }
    }
}

extern "C" void kernel_launch(void* const* d_in, const int* in_sizes, int n_in,
                              void* d_out, int out_size, void* d_ws, size_t ws_size,
                              hipStream_t stream) {
    const float* clss  = (const float*)d_in[0];  // [B,N,2]
    const float* regs  = (const float*)d_in[1];  // [B,N,4]
    const float* qlts  = (const float*)d_in[2];  // [B,N,1]
    const float* props = (const float*)d_in[3];  // [B,N,4]
    float* out = (float*)d_out;

    int B = in_sizes[0] / (NPROP * NCLS);

    PRISM_71511205479155_kernel<<<B, BT, 0, stream>>>(clss, regs, qlts, props, out, B);
}

// Round 4
// 63.675 us; speedup vs baseline: 5.0546x; 1.2156x over previous
//
#include <hip/hip_runtime.h>
#include <stdint.h>

#define NPROP 2048
#define NCLS  2
#define KDET  100
#define BT    512
#define NMS_TH 0.4f

// decode the monotone-encoded score from the high word of a sort key
__device__ __forceinline__ float dec_score(uint64_t k) {
    uint32_t u = ~(uint32_t)(k >> 32);
    uint32_t bits = (u & 0x80000000u) ? (u & 0x7FFFFFFFu) : ~u;
    return __uint_as_float(bits);
}

// IoU on class-offset boxes, rounding-identical to the reference
__device__ __forceinline__ float iou_off(float4 a, float4 b, float off) {
    float ax1 = __fadd_rn(a.x, off), ay1 = __fadd_rn(a.y, off);
    float ax2 = __fadd_rn(a.z, off), ay2 = __fadd_rn(a.w, off);
    float bx1 = __fadd_rn(b.x, off), by1 = __fadd_rn(b.y, off);
    float bx2 = __fadd_rn(b.z, off), by2 = __fadd_rn(b.w, off);
    float aA = __fmul_rn(__fsub_rn(ax2, ax1), __fsub_rn(ay2, ay1));
    float aB = __fmul_rn(__fsub_rn(bx2, bx1), __fsub_rn(by2, by1));
    float ltx = fmaxf(ax1, bx1), lty = fmaxf(ay1, by1);
    float rbx = fminf(ax2, bx2), rby = fminf(ay2, by2);
    float iw = fmaxf(__fsub_rn(rbx, ltx), 0.0f);
    float ih = fmaxf(__fsub_rn(rby, lty), 0.0f);
    float inter = __fmul_rn(iw, ih);
    float denom = __fadd_rn(__fsub_rn(__fadd_rn(aA, aB), inter), 1e-9f);
    return __fdiv_rn(inter, denom);
}

__global__ __launch_bounds__(BT) void PRISM_71511205479155_kernel(
    const float* __restrict__ clss,   // [B,N,2]
    const float* __restrict__ regs,   // [B,N,4]
    const float* __restrict__ qlts,   // [B,N]
    const float* __restrict__ props,  // [B,N,4]
    float* __restrict__ out,          // boxes[B*K*4] | scores[B*K] | classes[B*K]
    int B)
{
    __shared__ float4   sbox[NPROP];        // decoded+clipped boxes (orig coords)
    __shared__ uint64_t skey[NPROP];        // sorted keys (published after reg-sort)
    __shared__ unsigned long long s_rowmask[64];
    __shared__ unsigned long long s_insup;
    __shared__ int s_keep[KDET];            // sorted positions of keepers
    __shared__ int s_maxc, s_kept, s_nvalid;

    const int b    = blockIdx.x;
    const int tid  = threadIdx.x;
    const int lane = tid & 63;
    const int wv   = tid >> 6;               // 8 waves
    const int idxBase = (wv << 8) | lane;    // element idx(r) = idxBase + (r<<6)
    const float CLIPV = 4.135166556742356f;  // log(1000/16)

    if (tid == 0) { s_maxc = 0; s_kept = 0; s_nvalid = NPROP; }

    // ---- Phase A: decode, clip, score, build sort keys (4 elems/thread, in regs) ----
    uint64_t key[4];
#pragma unroll
    for (int r = 0; r < 4; ++r) {
        int i = idxBase + (r << 6);
        float4 p = ((const float4*)props)[b * NPROP + i];
        float4 rg = ((const float4*)regs)[b * NPROP + i];
        float c0 = clss[((size_t)b * NPROP + i) * 2 + 0];
        float c1 = clss[((size_t)b * NPROP + i) * 2 + 1];
        float qv = qlts[(size_t)b * NPROP + i];

        float w  = __fsub_rn(p.z, p.x);
        float h  = __fsub_rn(p.w, p.y);
        float cx = __fadd_rn(p.x, __fmul_rn(0.5f, w));
        float cy = __fadd_rn(p.y, __fmul_rn(0.5f, h));
        float dx = __fdiv_rn(rg.x, 10.0f);
        float dy = __fdiv_rn(rg.y, 10.0f);
        float dw = fminf(__fdiv_rn(rg.z, 5.0f), CLIPV);
        float dh = fminf(__fdiv_rn(rg.w, 5.0f), CLIPV);
        float pcx = __fadd_rn(__fmul_rn(dx, w), cx);
        float pcy = __fadd_rn(__fmul_rn(dy, h), cy);
        float pw  = __fmul_rn(expf(dw), w);
        float ph  = __fmul_rn(expf(dh), h);
        float x1 = __fsub_rn(pcx, __fmul_rn(0.5f, pw));
        float y1 = __fsub_rn(pcy, __fmul_rn(0.5f, ph));
        float x2 = __fadd_rn(pcx, __fmul_rn(0.5f, pw));
        float y2 = __fadd_rn(pcy, __fmul_rn(0.5f, ph));
        x1 = fminf(fmaxf(x1, 0.0f), 512.0f);
        y1 = fminf(fmaxf(y1, 0.0f), 512.0f);
        x2 = fminf(fmaxf(x2, 0.0f), 512.0f);
        y2 = fminf(fmaxf(y2, 0.0f), 512.0f);
        bool small_ok = (__fsub_rn(x2, x1) >= 0.01f) && (__fsub_rn(y2, y1) >= 0.01f);

        float m  = fmaxf(c0, c1);
        float e0 = expf(__fsub_rn(c0, m));
        float e1 = expf(__fsub_rn(c1, m));
        float raw = __fdiv_rn(e1, __fadd_rn(e0, e1));
        float sq  = __fdiv_rn(1.0f, __fadd_rn(1.0f, expf(-qv)));
        float score = __fmul_rn(sq, raw);
        bool valid = (raw > 0.05f) && small_ok;
        float masked = valid ? score : -1.0f;

        sbox[i] = make_float4(x1, y1, x2, y2);
        uint32_t fb = __float_as_uint(masked);
        uint32_t u  = (fb & 0x80000000u) ? ~fb : (fb | 0x80000000u); // monotone encode
        key[r] = ((uint64_t)(~u) << 32) | (uint32_t)i;               // asc = score desc, idx asc

        int mc = __float_as_int(fmaxf(fmaxf(x1, y1), fmaxf(x2, y2)));
        atomicMax(&s_maxc, mc);
    }

    // ---- Phase B: bitonic sort of 2048 keys, register-resident ----
    // idx(r) = idxBase + (r<<6): j<=32 -> shfl_xor; j=64 -> regs (0,1),(2,3);
    // j=128 -> regs (0,2),(1,3); j>=256 -> LDS exchange.
    for (int k = 2; k <= NPROP; k <<= 1) {
        for (int j = k >> 1; j > 0; j >>= 1) {
            if (j >= 256) {
                __syncthreads();
#pragma unroll
                for (int r = 0; r < 4; ++r) skey[idxBase + (r << 6)] = key[r];
                __syncthreads();
#pragma unroll
                for (int r = 0; r < 4; ++r) {
                    int idx = idxBase + (r << 6);
                    uint64_t o = skey[idx ^ j];
                    bool takeMin = (((idx & k) == 0) == ((idx & j) == 0));
                    bool lt = key[r] < o;
                    uint64_t mn = lt ? key[r] : o;
                    uint64_t mx = lt ? o : key[r];
                    key[r] = takeMin ? mn : mx;
                }
            } else if (j == 128) {
#pragma unroll
                for (int pr = 0; pr < 2; ++pr) {          // pairs (0,2),(1,3)
                    int rl = pr, rh = pr + 2;
                    int idx = idxBase + (rl << 6);
                    bool up = ((idx & k) == 0);
                    uint64_t a = key[rl], c2 = key[rh];
                    bool lt = a < c2;
                    uint64_t mn = lt ? a : c2, mx = lt ? c2 : a;
                    key[rl] = up ? mn : mx; key[rh] = up ? mx : mn;
                }
            } else if (j == 64) {
#pragma unroll
                for (int pr = 0; pr < 2; ++pr) {          // pairs (0,1),(2,3)
                    int rl = pr * 2, rh = rl + 1;
                    int idx = idxBase + (rl << 6);
                    bool up = ((idx & k) == 0);
                    uint64_t a = key[rl], c2 = key[rh];
                    bool lt = a < c2;
                    uint64_t mn = lt ? a : c2, mx = lt ? c2 : a;
                    key[rl] = up ? mn : mx; key[rh] = up ? mx : mn;
                }
            } else {
#pragma unroll
                for (int r = 0; r < 4; ++r) {
                    int idx = idxBase + (r << 6);
                    uint64_t o = __shfl_xor(key[r], j, 64);
                    bool takeMin = (((idx & k) == 0) == ((lane & j) == 0));
                    bool lt = key[r] < o;
                    uint64_t mn = lt ? key[r] : o;
                    uint64_t mx = lt ? o : key[r];
                    key[r] = takeMin ? mn : mx;
                }
            }
        }
    }
    // publish sorted keys for NMS
    __syncthreads();
#pragma unroll
    for (int r = 0; r < 4; ++r) skey[idxBase + (r << 6)] = key[r];
    __syncthreads();

    const float off = __fadd_rn(__int_as_float(s_maxc), 1.0f); // class-1 batched-NMS offset

    // ---- valid prefix length (invalid keys have top bit set) ----
    for (int idx = tid; idx < NPROP; idx += BT) {
        bool inval      = (skey[idx] >> 63) != 0;
        bool prev_inval = (idx == 0) ? false : ((skey[idx - 1] >> 63) != 0);
        if (inval && !prev_inval) s_nvalid = idx;   // unique writer
    }
    __syncthreads();

    // ---- Phase C: windowed greedy NMS (exact reference semantics) ----
    int c = 0;
    while (true) {
        __syncthreads();
        int kept = s_kept;
        int nv   = s_nvalid;
        if (c >= nv || kept >= KDET) break;
        int W = min(64, nv - c);
        if (tid == 0) s_insup = 0ull;
        __syncthreads();

        // this lane's window-candidate box (column l = lane)
        float4 qb = make_float4(0.f, 0.f, 0.f, 0.f);
        bool have = (lane < W);
        if (have) qb = sbox[(uint32_t)skey[c + lane]];

        // in-window pairwise suppression rows via ballot (8 waves x 8 rows)
        for (int i = wv; i < W; i += 8) {
            float4 ib = sbox[(uint32_t)skey[c + i]];
            bool pred = have && (lane > i) && (iou_off(ib, qb, off) > NMS_TH);
            unsigned long long bm = __ballot(pred);
            if (lane == 0) s_rowmask[i] = bm;
        }

        // incoming suppression by prior-window keepers
        if (have) {
            for (int ki = wv; ki < kept; ki += 8) {
                float4 kb = sbox[(uint32_t)skey[s_keep[ki]]];
                if (iou_off(kb, qb, off) > NMS_TH) {
                    atomicOr(&s_insup, 1ull << lane);
                    break;
                }
            }
        }
        __syncthreads();

        // serial greedy resolve of the window — wave 0, all in registers
        if (wv == 0) {
            unsigned long long rm = (lane < W) ? s_rowmask[lane] : 0ull;
            unsigned long long insup = s_insup;
            unsigned long long sup = 0ull;
            int k2 = kept;
            for (int i = 0; i < W; ++i) {
                if (k2 >= KDET) break;
                unsigned long long m = __shfl(rm, i);
                if (!((insup >> i) & 1ull) && !((sup >> i) & 1ull)) {
                    if (lane == 0) s_keep[k2] = c + i;
                    k2++;
                    sup |= m;
                }
            }
            if (lane == 0) s_kept = k2;
        }
        c += W;
    }
    __syncthreads();

    // ---- Phase D: parallel output write + zero-fill ----
    float* out_boxes  = out;
    float* out_scores = out + (size_t)B * KDET * 4;
    float* out_cls    = out + (size_t)B * KDET * 5;
    int kept = s_kept;
    for (int s = tid; s < KDET; s += BT) {
        float* ob = out_boxes + ((size_t)b * KDET + s) * 4;
        if (s < kept) {
            uint64_t kk = skey[s_keep[s]];
            float4 bx = sbox[(uint32_t)kk];
            ob[0] = bx.x; ob[1] = bx.y; ob[2] = bx.z; ob[3] = bx.w;
            out_scores[(size_t)b * KDET + s] = dec_score(kk);
            out_cls[(size_t)b * KDET + s]    = 1.0f;
        } else {
            ob[0] = 0.0f; ob[1] = 0.0f; ob[2] = 0.0f; ob[3] = 0.0f;
            out_scores[(size_t)b * KDET + s] = 0.0f;
            out_cls[(size_t)b * KDET + s]    = 0.0f;
        }
    }
}

extern "C" void kernel_launch(void* const* d_in, const int* in_sizes, int n_in,
                              void* d_out, int out_size, void* d_ws, size_t ws_size,
                              hipStream_t stream) {
    const float* clss  = (const float*)d_in[0];  // [B,N,2]
    const float* regs  = (const float*)d_in[1];  // [B,N,4]
    const float* qlts  = (const float*)d_in[2];  // [B,N,1]
    const float* props = (const float*)d_in[3];  // [B,N,4]
    float* out = (float*)d_out;

    int B = in_sizes[0] / (NPROP * NCLS);

    PRISM_71511205479155_kernel<<<B, BT, 0, stream>>>(clss, regs, qlts, props, out, B);
}

// Round 5
// 54.983 us; speedup vs baseline: 5.8537x; 1.1581x over previous
//
#include <hip/hip_runtime.h>
#include <stdint.h>

#define NPROP 2048
#define NCLS  2
#define KDET  100
#define BT    512
#define NMS_TH 0.4f

// decode the monotone-encoded score from the high word of a sort key
__device__ __forceinline__ float dec_score(uint64_t k) {
    uint32_t u = ~(uint32_t)(k >> 32);
    uint32_t bits = (u & 0x80000000u) ? (u & 0x7FFFFFFFu) : ~u;
    return __uint_as_float(bits);
}

// IoU on class-offset boxes, rounding-identical to the reference
__device__ __forceinline__ float iou_off(float4 a, float4 b, float off) {
    float ax1 = __fadd_rn(a.x, off), ay1 = __fadd_rn(a.y, off);
    float ax2 = __fadd_rn(a.z, off), ay2 = __fadd_rn(a.w, off);
    float bx1 = __fadd_rn(b.x, off), by1 = __fadd_rn(b.y, off);
    float bx2 = __fadd_rn(b.z, off), by2 = __fadd_rn(b.w, off);
    float aA = __fmul_rn(__fsub_rn(ax2, ax1), __fsub_rn(ay2, ay1));
    float aB = __fmul_rn(__fsub_rn(bx2, bx1), __fsub_rn(by2, by1));
    float ltx = fmaxf(ax1, bx1), lty = fmaxf(ay1, by1);
    float rbx = fminf(ax2, bx2), rby = fminf(ay2, by2);
    float iw = fmaxf(__fsub_rn(rbx, ltx), 0.0f);
    float ih = fmaxf(__fsub_rn(rby, lty), 0.0f);
    float inter = __fmul_rn(iw, ih);
    float denom = __fadd_rn(__fsub_rn(__fadd_rn(aA, aB), inter), 1e-9f);
    return __fdiv_rn(inter, denom);
}

__global__ __launch_bounds__(BT) void PRISM_71511205479155_kernel(
    const float* __restrict__ clss,   // [B,N,2]
    const float* __restrict__ regs,   // [B,N,4]
    const float* __restrict__ qlts,   // [B,N]
    const float* __restrict__ props,  // [B,N,4]
    float* __restrict__ out,          // boxes[B*K*4] | scores[B*K] | classes[B*K]
    int B)
{
    __shared__ float4   sbox[NPROP];          // decoded+clipped boxes (orig coords)
    __shared__ uint64_t skey[NPROP];          // sorted keys
    __shared__ uint64_t s_colpart[8 * 64];    // per-wave partial column masks
    __shared__ uint64_t s_inpart[8];          // per-wave incoming-suppression ballots
    __shared__ float4   s_kbox[KDET];         // keeper boxes (contiguous cache)
    __shared__ int      s_keep[KDET];         // sorted positions of keepers
    __shared__ int      s_maxc, s_kept, s_nvalid;

    const int b    = blockIdx.x;
    const int tid  = threadIdx.x;
    const int lane = tid & 63;
    const int wv   = tid >> 6;               // 8 waves
    const int idxBase = (wv << 8) | lane;    // element idx(r) = idxBase + (r<<6)
    const float CLIPV = 4.135166556742356f;  // log(1000/16)

    if (tid == 0) { s_maxc = 0; s_kept = 0; s_nvalid = NPROP; }

    // ---- Phase A: decode, clip, score, build sort keys (4 elems/thread) ----
    uint64_t key[4];
    float thmax = 0.0f;
#pragma unroll
    for (int r = 0; r < 4; ++r) {
        int i = idxBase + (r << 6);
        float4 p  = ((const float4*)props)[b * NPROP + i];
        float4 rg = ((const float4*)regs)[b * NPROP + i];
        float2 cc = ((const float2*)clss)[b * NPROP + i];
        float  qv = qlts[(size_t)b * NPROP + i];

        float w  = __fsub_rn(p.z, p.x);
        float h  = __fsub_rn(p.w, p.y);
        float cx = __fadd_rn(p.x, __fmul_rn(0.5f, w));
        float cy = __fadd_rn(p.y, __fmul_rn(0.5f, h));
        float dx = __fdiv_rn(rg.x, 10.0f);
        float dy = __fdiv_rn(rg.y, 10.0f);
        float dw = fminf(__fdiv_rn(rg.z, 5.0f), CLIPV);
        float dh = fminf(__fdiv_rn(rg.w, 5.0f), CLIPV);
        float pcx = __fadd_rn(__fmul_rn(dx, w), cx);
        float pcy = __fadd_rn(__fmul_rn(dy, h), cy);
        float pw  = __fmul_rn(expf(dw), w);
        float ph  = __fmul_rn(expf(dh), h);
        float x1 = __fsub_rn(pcx, __fmul_rn(0.5f, pw));
        float y1 = __fsub_rn(pcy, __fmul_rn(0.5f, ph));
        float x2 = __fadd_rn(pcx, __fmul_rn(0.5f, pw));
        float y2 = __fadd_rn(pcy, __fmul_rn(0.5f, ph));
        x1 = fminf(fmaxf(x1, 0.0f), 512.0f);
        y1 = fminf(fmaxf(y1, 0.0f), 512.0f);
        x2 = fminf(fmaxf(x2, 0.0f), 512.0f);
        y2 = fminf(fmaxf(y2, 0.0f), 512.0f);
        bool small_ok = (__fsub_rn(x2, x1) >= 0.01f) && (__fsub_rn(y2, y1) >= 0.01f);

        float m  = fmaxf(cc.x, cc.y);
        float e0 = expf(__fsub_rn(cc.x, m));
        float e1 = expf(__fsub_rn(cc.y, m));
        float raw = __fdiv_rn(e1, __fadd_rn(e0, e1));
        float sq  = __fdiv_rn(1.0f, __fadd_rn(1.0f, expf(-qv)));
        float score = __fmul_rn(sq, raw);
        bool valid = (raw > 0.05f) && small_ok;
        float masked = valid ? score : -1.0f;

        sbox[i] = make_float4(x1, y1, x2, y2);
        uint32_t fb = __float_as_uint(masked);
        uint32_t u  = (fb & 0x80000000u) ? ~fb : (fb | 0x80000000u); // monotone encode
        key[r] = ((uint64_t)(~u) << 32) | (uint32_t)i;               // asc = score desc, idx asc

        thmax = fmaxf(thmax, fmaxf(fmaxf(x1, y1), fmaxf(x2, y2)));
    }
    atomicMax(&s_maxc, __float_as_int(thmax));   // coords >= 0: int cmp == float cmp

    // ---- Phase B: bitonic sort of 2048 keys, register-resident ----
    for (int k = 2; k <= NPROP; k <<= 1) {
        for (int j = k >> 1; j > 0; j >>= 1) {
            if (j >= 256) {
                __syncthreads();
#pragma unroll
                for (int r = 0; r < 4; ++r) skey[idxBase + (r << 6)] = key[r];
                __syncthreads();
#pragma unroll
                for (int r = 0; r < 4; ++r) {
                    int idx = idxBase + (r << 6);
                    uint64_t o = skey[idx ^ j];
                    bool takeMin = (((idx & k) == 0) == ((idx & j) == 0));
                    bool lt = key[r] < o;
                    uint64_t mn = lt ? key[r] : o;
                    uint64_t mx = lt ? o : key[r];
                    key[r] = takeMin ? mn : mx;
                }
            } else if (j == 128) {
#pragma unroll
                for (int pr = 0; pr < 2; ++pr) {          // pairs (0,2),(1,3)
                    int rl = pr, rh = pr + 2;
                    int idx = idxBase + (rl << 6);
                    bool up = ((idx & k) == 0);
                    uint64_t a = key[rl], c2 = key[rh];
                    bool lt = a < c2;
                    uint64_t mn = lt ? a : c2, mx = lt ? c2 : a;
                    key[rl] = up ? mn : mx; key[rh] = up ? mx : mn;
                }
            } else if (j == 64) {
#pragma unroll
                for (int pr = 0; pr < 2; ++pr) {          // pairs (0,1),(2,3)
                    int rl = pr * 2, rh = rl + 1;
                    int idx = idxBase + (rl << 6);
                    bool up = ((idx & k) == 0);
                    uint64_t a = key[rl], c2 = key[rh];
                    bool lt = a < c2;
                    uint64_t mn = lt ? a : c2, mx = lt ? c2 : a;
                    key[rl] = up ? mn : mx; key[rh] = up ? mx : mn;
                }
            } else {
#pragma unroll
                for (int r = 0; r < 4; ++r) {
                    int idx = idxBase + (r << 6);
                    uint64_t o = __shfl_xor(key[r], j, 64);
                    bool takeMin = (((idx & k) == 0) == ((lane & j) == 0));
                    bool lt = key[r] < o;
                    uint64_t mn = lt ? key[r] : o;
                    uint64_t mx = lt ? o : key[r];
                    key[r] = takeMin ? mn : mx;
                }
            }
        }
    }
    __syncthreads();
#pragma unroll
    for (int r = 0; r < 4; ++r) skey[idxBase + (r << 6)] = key[r];
    __syncthreads();

    const float off = __fadd_rn(__int_as_float(s_maxc), 1.0f); // class-1 batched-NMS offset

    // ---- valid prefix length (invalid keys have top bit set) ----
    for (int idx = tid; idx < NPROP; idx += BT) {
        bool inval      = (skey[idx] >> 63) != 0;
        bool prev_inval = (idx == 0) ? false : ((skey[idx - 1] >> 63) != 0);
        if (inval && !prev_inval) s_nvalid = idx;   // unique writer
    }

    // ---- Phase C: windowed greedy NMS (exact reference semantics) ----
    int c = 0;
    while (true) {
        __syncthreads();
        int kept = s_kept;
        int nv   = s_nvalid;
        if (c >= nv || kept >= KDET) break;
        int W = min(64, nv - c);

        // this lane's window-candidate box (column = lane)
        float4 qb = make_float4(0.f, 0.f, 0.f, 0.f);
        bool have = (lane < W);
        if (have) qb = sbox[(uint32_t)skey[c + lane]];

        // in-window pairwise rows via ballot; accumulate OWN column bits
        uint64_t colpart = 0;
        for (int i = wv; i < W; i += 8) {
            float4 ib = sbox[(uint32_t)skey[c + i]];
            bool pred = have && (lane > i) && (iou_off(ib, qb, off) > NMS_TH);
            unsigned long long bm = __ballot(pred);
            colpart |= ((bm >> lane) & 1ull) << i;
        }
        s_colpart[(wv << 6) | lane] = colpart;

        // incoming suppression by prior-window keepers (cached boxes, branch-free)
        bool supin = false;
        if (have) {
            for (int ki = wv; ki < kept; ki += 8) {
                if (iou_off(s_kbox[ki], qb, off) > NMS_TH) supin = true;
            }
        }
        unsigned long long inb = __ballot(supin);
        if (lane == 0) s_inpart[wv] = inb;
        __syncthreads();

        // ballot-driven greedy resolve of the window — wave 0, no shuffles
        if (wv == 0) {
            uint64_t col = 0;
#pragma unroll
            for (int w2 = 0; w2 < 8; ++w2) col |= s_colpart[(w2 << 6) | lane];
            uint64_t insup = 0;
#pragma unroll
            for (int w2 = 0; w2 < 8; ++w2) insup |= s_inpart[w2];

            bool killed = ((insup >> lane) & 1ull) != 0ull;
            uint64_t remain = (W == 64) ? ~0ull : ((1ull << W) - 1ull);
            int k2 = kept;
            int myNew = 0;
            while (k2 < KDET) {
                uint64_t aliveB = (uint64_t)__ballot(!killed) & remain;
                if (!aliveB) break;
                int i = (int)__builtin_ctzll(aliveB);     // next keeper
                if (lane == (k2 - kept)) myNew = i;       // capture per-keeper idx
                if (lane == 0) s_keep[k2] = c + i;
                k2++;
                killed = killed || (((col >> i) & 1ull) != 0ull);
                remain = (i < 63) ? (remain & (~0ull << (i + 1))) : 0ull;
            }
            int nNew = k2 - kept;
            if (lane == 0) s_kept = k2;
            if (lane < nNew) {                            // cache keeper boxes
                uint64_t kk = skey[c + myNew];
                s_kbox[kept + lane] = sbox[(uint32_t)kk];
            }
        }
        c += W;
    }
    __syncthreads();

    // ---- Phase D: parallel output write + zero-fill ----
    float* out_boxes  = out;
    float* out_scores = out + (size_t)B * KDET * 4;
    float* out_cls    = out + (size_t)B * KDET * 5;
    int kept = s_kept;
    for (int s = tid; s < KDET; s += BT) {
        float* ob = out_boxes + ((size_t)b * KDET + s) * 4;
        if (s < kept) {
            uint64_t kk = skey[s_keep[s]];
            float4 bx = sbox[(uint32_t)kk];
            ob[0] = bx.x; ob[1] = bx.y; ob[2] = bx.z; ob[3] = bx.w;
            out_scores[(size_t)b * KDET + s] = dec_score(kk);
            out_cls[(size_t)b * KDET + s]    = 1.0f;
        } else {
            ob[0] = 0.0f; ob[1] = 0.0f; ob[2] = 0.0f; ob[3] = 0.0f;
            out_scores[(size_t)b * KDET + s] = 0.0f;
            out_cls[(size_t)b * KDET + s]    = 0.0f;
        }
    }
}

extern "C" void kernel_launch(void* const* d_in, const int* in_sizes, int n_in,
                              void* d_out, int out_size, void* d_ws, size_t ws_size,
                              hipStream_t stream) {
    const float* clss  = (const float*)d_in[0];  // [B,N,2]
    const float* regs  = (const float*)d_in[1];  // [B,N,4]
    const float* qlts  = (const float*)d_in[2];  // [B,N,1]
    const float* props = (const float*)d_in[3];  // [B,N,4]
    float* out = (float*)d_out;

    int B = in_sizes[0] / (NPROP * NCLS);

    PRISM_71511205479155_kernel<<<B, BT, 0, stream>>>(clss, regs, qlts, props, out, B);
}

// Round 6
// 52.428 us; speedup vs baseline: 6.1390x; 1.0487x over previous
//
#include <hip/hip_runtime.h>
#include <stdint.h>

#define NPROP 2048
#define NCLS  2
#define KDET  100
#define BT    512
#define NMS_TH 0.4f

// decode the monotone-encoded score from the high word of a sort key
__device__ __forceinline__ float dec_score(uint64_t k) {
    uint32_t u = ~(uint32_t)(k >> 32);
    uint32_t bits = (u & 0x80000000u) ? (u & 0x7FFFFFFFu) : ~u;
    return __uint_as_float(bits);
}

__global__ __launch_bounds__(BT) void PRISM_71511205479155_kernel(
    const float* __restrict__ clss,   // [B,N,2]
    const float* __restrict__ regs,   // [B,N,4]
    const float* __restrict__ qlts,   // [B,N]
    const float* __restrict__ props,  // [B,N,4]
    float* __restrict__ out,          // boxes[B*K*4] | scores[B*K] | classes[B*K]
    int B)
{
    __shared__ float4   sbox[NPROP];          // decoded+clipped boxes (orig coords)
    __shared__ uint64_t skey[NPROP];          // sort scratch (phi layout) / sorted keys (true layout)
    __shared__ uint64_t s_colpart[8 * 64];    // per-wave partial column masks
    __shared__ uint64_t s_inpart[8];          // per-wave incoming-suppression ballots
    __shared__ float4   s_kbox[KDET];         // keeper boxes in OFFSET coords
    __shared__ float    s_karea[KDET];        // keeper areas (offset coords)
    __shared__ int      s_keep[KDET];         // sorted positions of keepers
    __shared__ int      s_maxc, s_kept, s_nvalid;

    const int b    = blockIdx.x;
    const int tid  = threadIdx.x;
    const int lane = tid & 63;
    const int wv   = tid >> 6;                  // 8 waves
    const int idxBase = (wv << 8) | (lane << 2); // element idx(r) = idxBase + r (consecutive!)
    const float CLIPV = 4.135166556742356f;     // log(1000/16)

    if (tid == 0) { s_maxc = 0; s_kept = 0; s_nvalid = NPROP; }
    __syncthreads();   // init visible before any atomic below

    // ---- Phase A: decode, clip, score, build sort keys (4 consecutive elems/thread) ----
    uint64_t key[4];
    float thmax = 0.0f;
#pragma unroll
    for (int r = 0; r < 4; ++r) {
        int i = idxBase + r;
        float4 p  = ((const float4*)props)[b * NPROP + i];
        float4 rg = ((const float4*)regs)[b * NPROP + i];
        float2 cc = ((const float2*)clss)[b * NPROP + i];
        float  qv = qlts[(size_t)b * NPROP + i];

        float w  = __fsub_rn(p.z, p.x);
        float h  = __fsub_rn(p.w, p.y);
        float cx = __fadd_rn(p.x, __fmul_rn(0.5f, w));
        float cy = __fadd_rn(p.y, __fmul_rn(0.5f, h));
        float dx = __fdiv_rn(rg.x, 10.0f);
        float dy = __fdiv_rn(rg.y, 10.0f);
        float dw = fminf(__fdiv_rn(rg.z, 5.0f), CLIPV);
        float dh = fminf(__fdiv_rn(rg.w, 5.0f), CLIPV);
        float pcx = __fadd_rn(__fmul_rn(dx, w), cx);
        float pcy = __fadd_rn(__fmul_rn(dy, h), cy);
        float pw  = __fmul_rn(expf(dw), w);
        float ph  = __fmul_rn(expf(dh), h);
        float x1 = __fsub_rn(pcx, __fmul_rn(0.5f, pw));
        float y1 = __fsub_rn(pcy, __fmul_rn(0.5f, ph));
        float x2 = __fadd_rn(pcx, __fmul_rn(0.5f, pw));
        float y2 = __fadd_rn(pcy, __fmul_rn(0.5f, ph));
        x1 = fminf(fmaxf(x1, 0.0f), 512.0f);
        y1 = fminf(fmaxf(y1, 0.0f), 512.0f);
        x2 = fminf(fmaxf(x2, 0.0f), 512.0f);
        y2 = fminf(fmaxf(y2, 0.0f), 512.0f);
        bool small_ok = (__fsub_rn(x2, x1) >= 0.01f) && (__fsub_rn(y2, y1) >= 0.01f);

        float m  = fmaxf(cc.x, cc.y);
        float e0 = expf(__fsub_rn(cc.x, m));
        float e1 = expf(__fsub_rn(cc.y, m));
        float raw = __fdiv_rn(e1, __fadd_rn(e0, e1));
        float sq  = __fdiv_rn(1.0f, __fadd_rn(1.0f, expf(-qv)));
        float score = __fmul_rn(sq, raw);
        bool valid = (raw > 0.05f) && small_ok;
        float masked = valid ? score : -1.0f;

        sbox[i] = make_float4(x1, y1, x2, y2);
        uint32_t fb = __float_as_uint(masked);
        uint32_t u  = (fb & 0x80000000u) ? ~fb : (fb | 0x80000000u); // monotone encode
        key[r] = ((uint64_t)(~u) << 32) | (uint32_t)i;               // asc = score desc, idx asc

        thmax = fmaxf(thmax, fmaxf(fmaxf(x1, y1), fmaxf(x2, y2)));
    }
    atomicMax(&s_maxc, __float_as_int(thmax));   // coords >= 0: int cmp == float cmp

    // ---- Phase B: bitonic sort of 2048 keys ----
    // idx = [wv(3b)][lane(6b)][r(2b)]: j<=2 -> register; 4<=j<=128 -> shfl_xor(j>>2);
    // j>=256 -> LDS via phi-swizzled storage phi(idx) = (idx>>2) | ((idx&3)<<9).
    for (int k = 2; k <= NPROP; k <<= 1) {
        for (int j = k >> 1; j > 0; j >>= 1) {
            if (j >= 256) {
                __syncthreads();
#pragma unroll
                for (int r = 0; r < 4; ++r) {
                    int idx = idxBase + r;
                    skey[(idx >> 2) | ((idx & 3) << 9)] = key[r];
                }
                __syncthreads();
#pragma unroll
                for (int r = 0; r < 4; ++r) {
                    int idx  = idxBase + r;
                    int pidx = idx ^ j;
                    uint64_t o = skey[(pidx >> 2) | ((pidx & 3) << 9)];
                    bool takeMin = (((idx & k) == 0) == ((idx & j) == 0));
                    bool lt = key[r] < o;
                    uint64_t mn = lt ? key[r] : o, mx = lt ? o : key[r];
                    key[r] = takeMin ? mn : mx;
                }
            } else if (j >= 4) {
                int lx = j >> 2;
#pragma unroll
                for (int r = 0; r < 4; ++r) {
                    int idx = idxBase + r;
                    uint64_t o = __shfl_xor(key[r], lx, 64);
                    bool takeMin = (((idx & k) == 0) == ((lane & lx) == 0));
                    bool lt = key[r] < o;
                    uint64_t mn = lt ? key[r] : o, mx = lt ? o : key[r];
                    key[r] = takeMin ? mn : mx;
                }
            } else {
                // j == 1 or 2: register pairs (r, r|j)
#pragma unroll
                for (int r = 0; r < 4; ++r) {
                    if ((r & j) == 0) {
                        int rh = r | j;
                        int idx = idxBase + r;
                        bool up = ((idx & k) == 0);
                        uint64_t a = key[r], c2 = key[rh];
                        bool lt = a < c2;
                        uint64_t mn = lt ? a : c2, mx = lt ? c2 : a;
                        key[r] = up ? mn : mx; key[rh] = up ? mx : mn;
                    }
                }
            }
        }
    }

    // publish sorted keys at TRUE layout (barrier: last LDS-stage reads must finish)
    __syncthreads();
#pragma unroll
    for (int r = 0; r < 4; ++r) skey[idxBase + r] = key[r];

    // valid prefix length from registers: first element with top bit set
    {
        int fi = 4;
#pragma unroll
        for (int r = 3; r >= 0; --r) if ((key[r] >> 63) != 0) fi = r;
        uint64_t anyb = __ballot(fi < 4);
        if (anyb) {
            int L = (int)__builtin_ctzll(anyb);
            int fiL = __shfl(fi, L);
            if (lane == 0) atomicMin(&s_nvalid, (wv << 8) + (L << 2) + fiL);
        }
    }
    __syncthreads();

    const float off = __fadd_rn(__int_as_float(s_maxc), 1.0f); // class-1 batched-NMS offset

    // ---- Phase C: windowed greedy NMS (exact reference semantics) ----
    int c = 0;
    while (true) {
        __syncthreads();
        int kept = s_kept;
        int nv   = s_nvalid;
        if (c >= nv || kept >= KDET) break;
        int W = min(64, nv - c);
        bool have = (lane < W);

        // this lane's candidate in OFFSET coords + area (reference op order)
        float qx1 = 0.f, qy1 = 0.f, qx2 = 0.f, qy2 = 0.f, qa = 0.f;
        if (have) {
            float4 bx = sbox[(uint32_t)skey[c + lane]];
            qx1 = __fadd_rn(bx.x, off); qy1 = __fadd_rn(bx.y, off);
            qx2 = __fadd_rn(bx.z, off); qy2 = __fadd_rn(bx.w, off);
            qa  = __fmul_rn(__fsub_rn(qx2, qx1), __fsub_rn(qy2, qy1));
        }

        // in-window rows via shuffle broadcast; accumulate OWN column bits
        uint64_t colpart = 0;
#pragma unroll
        for (int t = 0; t < 8; ++t) {
            int i = wv + (t << 3);
            bool rowok = (i < W);
            int isrc = rowok ? i : 0;
            float rx1 = __shfl(qx1, isrc, 64);
            float ry1 = __shfl(qy1, isrc, 64);
            float rx2 = __shfl(qx2, isrc, 64);
            float ry2 = __shfl(qy2, isrc, 64);
            float ra  = __shfl(qa , isrc, 64);
            float ltx = fmaxf(rx1, qx1), lty = fmaxf(ry1, qy1);
            float rbx = fminf(rx2, qx2), rby = fminf(ry2, qy2);
            float iw = fmaxf(__fsub_rn(rbx, ltx), 0.0f);
            float ih = fmaxf(__fsub_rn(rby, lty), 0.0f);
            float inter = __fmul_rn(iw, ih);
            float denom = __fadd_rn(__fsub_rn(__fadd_rn(ra, qa), inter), 1e-9f);
            float iou   = __fdiv_rn(inter, denom);
            bool pred = rowok && have && (lane > i) && (iou > NMS_TH);
            uint64_t bm = (uint64_t)__ballot(pred);
            colpart |= ((bm >> lane) & 1ull) << isrc;
        }
        s_colpart[(wv << 6) | lane] = colpart;

        // incoming suppression by prior-window keepers (offset boxes + areas cached)
        bool supin = false;
        if (have) {
            for (int ki = wv; ki < kept; ki += 8) {
                float4 ko = s_kbox[ki];
                float  ka = s_karea[ki];
                float ltx = fmaxf(ko.x, qx1), lty = fmaxf(ko.y, qy1);
                float rbx = fminf(ko.z, qx2), rby = fminf(ko.w, qy2);
                float iw = fmaxf(__fsub_rn(rbx, ltx), 0.0f);
                float ih = fmaxf(__fsub_rn(rby, lty), 0.0f);
                float inter = __fmul_rn(iw, ih);
                float denom = __fadd_rn(__fsub_rn(__fadd_rn(ka, qa), inter), 1e-9f);
                supin = supin || (__fdiv_rn(inter, denom) > NMS_TH);
            }
        }
        uint64_t inb = (uint64_t)__ballot(supin);
        if (lane == 0) s_inpart[wv] = inb;
        __syncthreads();

        // ballot-driven greedy resolve of the window — wave 0
        if (wv == 0) {
            uint64_t col = 0, insup = 0;
#pragma unroll
            for (int w2 = 0; w2 < 8; ++w2) {
                col   |= s_colpart[(w2 << 6) | lane];
                insup |= s_inpart[w2];
            }
            bool killed = ((insup >> lane) & 1ull) != 0ull;
            uint64_t remain = (W == 64) ? ~0ull : ((1ull << W) - 1ull);
            int k2 = kept;
            int myNew = 0;
            while (k2 < KDET) {
                uint64_t aliveB = (uint64_t)__ballot(!killed) & remain;
                if (!aliveB) break;
                int i = (int)__builtin_ctzll(aliveB);     // next keeper
                if (lane == (k2 - kept)) myNew = i;       // capture per-keeper idx
                if (lane == 0) s_keep[k2] = c + i;
                k2++;
                killed = killed || (((col >> i) & 1ull) != 0ull);
                remain = (i < 63) ? (remain & (~0ull << (i + 1))) : 0ull;
            }
            int nNew = k2 - kept;
            if (lane == 0) s_kept = k2;
            if (lane < nNew) {                            // cache keeper offset box + area
                float4 bx = sbox[(uint32_t)skey[c + myNew]];
                float kx1 = __fadd_rn(bx.x, off), ky1 = __fadd_rn(bx.y, off);
                float kx2 = __fadd_rn(bx.z, off), ky2 = __fadd_rn(bx.w, off);
                s_kbox[kept + lane]  = make_float4(kx1, ky1, kx2, ky2);
                s_karea[kept + lane] = __fmul_rn(__fsub_rn(kx2, kx1), __fsub_rn(ky2, ky1));
            }
        }
        c += W;
    }
    __syncthreads();

    // ---- Phase D: parallel output write + zero-fill ----
    float* out_boxes  = out;
    float* out_scores = out + (size_t)B * KDET * 4;
    float* out_cls    = out + (size_t)B * KDET * 5;
    int kept = s_kept;
    for (int s = tid; s < KDET; s += BT) {
        float* ob = out_boxes + ((size_t)b * KDET + s) * 4;
        if (s < kept) {
            uint64_t kk = skey[s_keep[s]];
            float4 bx = sbox[(uint32_t)kk];
            ob[0] = bx.x; ob[1] = bx.y; ob[2] = bx.z; ob[3] = bx.w;
            out_scores[(size_t)b * KDET + s] = dec_score(kk);
            out_cls[(size_t)b * KDET + s]    = 1.0f;
        } else {
            ob[0] = 0.0f; ob[1] = 0.0f; ob[2] = 0.0f; ob[3] = 0.0f;
            out_scores[(size_t)b * KDET + s] = 0.0f;
            out_cls[(size_t)b * KDET + s]    = 0.0f;
        }
    }
}

extern "C" void kernel_launch(void* const* d_in, const int* in_sizes, int n_in,
                              void* d_out, int out_size, void* d_ws, size_t ws_size,
                              hipStream_t stream) {
    const float* clss  = (const float*)d_in[0];  // [B,N,2]
    const float* regs  = (const float*)d_in[1];  // [B,N,4]
    const float* qlts  = (const float*)d_in[2];  // [B,N,1]
    const float* props = (const float*)d_in[3];  // [B,N,4]
    float* out = (float*)d_out;

    int B = in_sizes[0] / (NPROP * NCLS);

    PRISM_71511205479155_kernel<<<B, BT, 0, stream>>>(clss, regs, qlts, props, out, B);
}